// Round 29
// baseline (33.462 us; speedup 1.0000x reference)
//
#include <hip/hip_runtime.h>

// AnatomicalConsistencyLoss: fused separable-Sobel magnitude + cosine loss.
// pred/target (2,1,160,160,160) f32 -> scalar f32.
// R29 = R28 (combo-staged, load-balanced, 2-plane interval, best 28.41us)
// widened to THREE planes per barrier interval (18 = 6x3): barriers 9 -> 6,
// triple prefetch sets A/B/C (36 dwords), three consume chains interleave
// per quantum, staging cover ~2 intervals. EXPLICIT GAMBLE on the allocator
// wall (~76 live dwords): spill gate = WRITE_SIZE < 1MB, else R28 is final.
// Second risk: 6 LDS slots = 58.8KB -> 2 blocks/CU (OccupancyPercent will
// show if TLP drops too far). Everything else byte-identical to R28:
// 288 per-volume combo items over 256 threads (tid<32 take a second),
// misaligned v4+v2 raw loads, {HS.xy,HD.xy} interleaved LDS, mask-free
// consume, pending-sum z-stream, packed-v2 loss tail, XCD swizzle,
// DC=16/1000 blocks, two-kernel finalize, unroll pinned.

constexpr int Dd = 160, Hh = 160, Ww = 160;
constexpr int TW = 32, TH = 16, DC = 16;
constexpr int NTX = Ww / TW;                 // 5
constexpr int NTY = Hh / TH;                 // 10
constexpr int NTZ = Dd / DC;                 // 10
constexpr int NBLOCKS = NTX * NTY * NTZ * 2; // 1000
constexpr int NXCD = 8;
constexpr int CHUNK = NBLOCKS / NXCD;        // 125
constexpr int PLANES = DC + 2;               // 18 = 6 intervals x 3 planes
constexpr int PLSZ = Hh * Ww;                // 25600
constexpr double NVOX = 2.0 * Dd * Hh * Ww;  // 8,192,000

constexpr int CROWS = TH + 2;                // 18 combo rows
constexpr int CGP   = 17;                    // padded group stride (v4 units)

typedef float v2 __attribute__((ext_vector_type(2)));
typedef float v4 __attribute__((ext_vector_type(4)));
typedef float v4a __attribute__((ext_vector_type(4), aligned(4)));  // dword-aligned ok
typedef float v2a __attribute__((ext_vector_type(2), aligned(4)));

__global__ __launch_bounds__(256)
void acl_partial(const float* __restrict__ pred, const float* __restrict__ targ,
                 float2* __restrict__ partial)
{
    // {HS.xy, HD.xy} per 2-col group; b128-aligned; row stride 17 v4s (pad)
    __shared__ v4 cmb[6][2][CROWS][CGP];   // [slot][vol][row][grp], 58.8 KB
    __shared__ float rred[8];

    const int tid = threadIdx.x;
    const int gx  = tid & 15;        // consume: x-group of 2 output cols
    const int r   = tid >> 4;        // consume: row 0..15

    // ---- XCD-chunked bijective swizzle + decode (zt fastest, wt, ht, b) ----
    const int bid = blockIdx.x;
    const int swz = (bid % NXCD) * CHUNK + bid / NXCD;
    const int zt  = swz % NTZ;
    const int t1  = swz / NTZ;
    const int wt  = t1 % NTX;
    const int t2  = t1 / NTX;
    const int ht  = t2 % NTY;
    const int b   = t2 / NTY;

    const int x0 = wt * TW, y0 = ht * TH;
    const int z0 = zt * DC;
    const size_t base = (size_t)b * ((size_t)Dd * PLSZ);
    const float* __restrict__ pv = pred + base;
    const float* __restrict__ tv = targ + base;

    // ---- per-volume combo items: vitem v in [0,288): row=v>>4, sub=v&15,
    //      vol=sub&1, cg=sub>>1. Primary = tid; secondary (tid<32) = 256+tid.
    const bool hasSec = (tid < 32);

    struct ItemC { int a4, a2, bo; bool fixLo, fixHi, yok, isT; };
    auto mkItem = [&](int v, ItemC& it) {
        const int row = v >> 4;
        const int sub = v & 15;
        const int vol = sub & 1;
        const int cg  = sub >> 1;
        const int gy  = y0 - 1 + row;
        it.yok = (gy >= 0) && (gy < Hh);
        const int gycl = gy < 0 ? 0 : (gy > Hh - 1 ? Hh - 1 : gy);
        it.fixLo = (x0 == 0) && (cg == 0);
        it.fixHi = (x0 + TW == Ww) && (cg == 7);
        const int xb = x0 + 4 * cg - 1;
        it.a4 = gycl * Ww + (it.fixLo ? 0 : xb);              // v4: e0..e3 (or e1..e4)
        it.a2 = gycl * Ww + (it.fixHi ? (Ww - 2) : (xb + 4)); // v2: e4,e5 (or e3,e4)
        it.bo = (vol * CROWS + row) * CGP + 2 * cg;           // v4 offset in slot
        it.isT = (vol != 0);
    };
    ItemC itP, itS;
    mkItem(tid, itP);
    mkItem(hasSec ? 256 + tid : tid, itS);   // dummy for non-sec (never stored)

    const v2 z2 = {0.f, 0.f};
    const v4 z4 = {0.f, 0.f, 0.f, 0.f};

    // streaming pending partial gradients (named v2 scalars only)
    v2 P1x = z2, P1y = z2, P1z = z2, P2x = z2, P2y = z2, P2z = z2;
    v2 T1x = z2, T1y = z2, T1z = z2, T2x = z2, T2y = z2, T2z = z2;
    v2 accm = z2, accc = z2;

    // triple prefetch reg sets A/B/C (12 dwords each)
    v4 pA4 = z4, sA4 = z4, pB4 = z4, sB4 = z4, pC4 = z4, sC4 = z4;
    v2 pA2 = z2, sA2 = z2, pB2 = z2, sB2 = z2, pC2 = z2, sC2 = z2;

    auto issueG = [&](v4& q4, v2& q2, v4& s4, v2& s2, int p2) {
        int gz = z0 - 1 + p2;
        gz = gz < 0 ? 0 : (gz > Dd - 1 ? Dd - 1 : gz);
        const float* zp = (itP.isT ? tv : pv) + (ptrdiff_t)gz * PLSZ;
        q4 = *(const v4a*)(zp + itP.a4);
        q2 = *(const v2a*)(zp + itP.a2);
        if (hasSec) {
            const float* zs = (itS.isT ? tv : pv) + (ptrdiff_t)gz * PLSZ;
            s4 = *(const v4a*)(zs + itS.a4);
            s2 = *(const v2a*)(zs + itS.a2);
        }
    };

    // assemble e0..e5 from the two loads, honoring edge fixups
    auto comboOne = [&](const ItemC& it, const v4 v, const v2 u, v4& w0, v4& w1) {
        float e0, e1, e2, e3, e4, e5;
        if (it.fixLo)      { e0 = 0.f;  e1 = v.x; e2 = v.y; e3 = v.z; e4 = v.w; e5 = u.y; }
        else if (it.fixHi) { e0 = v.x;  e1 = v.y; e2 = v.z; e3 = v.w; e4 = u.y; e5 = 0.f; }
        else               { e0 = v.x;  e1 = v.y; e2 = v.z; e3 = v.w; e4 = u.x; e5 = u.y; }
        const float HS0 = e0 + 2.f*e1 + e2, HS1 = e1 + 2.f*e2 + e3;
        const float HS2 = e2 + 2.f*e3 + e4, HS3 = e3 + 2.f*e4 + e5;
        w0 = (v4){HS0, HS1, e2 - e0, e3 - e1};
        w1 = (v4){HS2, HS3, e4 - e2, e5 - e3};
    };

    auto comboWrite = [&](const v4 q4, const v2 q2, const v4 s4, const v2 s2,
                          int p1, int slot) {
        const bool zokc = ((unsigned)(z0 - 1 + p1) < (unsigned)Dd);
        v4* sb = &cmb[slot][0][0][0];
        v4 w0, w1;
        comboOne(itP, q4, q2, w0, w1);
        if (!(zokc && itP.yok)) { w0 = z4; w1 = z4; }
        sb[itP.bo]     = w0;
        sb[itP.bo + 1] = w1;
        if (hasSec) {
            comboOne(itS, s4, s2, w0, w1);
            if (!(zokc && itS.yok)) { w0 = z4; w1 = z4; }
            sb[itS.bo]     = w0;
            sb[itS.bo + 1] = w1;
        }
    };

    auto consume = [&](int p, int s) {
        const v4 qm = cmb[s][0][r][gx], q0 = cmb[s][0][r + 1][gx], qp = cmb[s][0][r + 2][gx];
        const v2 A = qm.xy + 2.f*q0.xy + qp.xy;   // sm_y(HS) -> z path
        const v2 B = qm.zw + 2.f*q0.zw + qp.zw;   // sm_y(HD) -> x grad
        const v2 C = qp.xy - qm.xy;               // d_y(HS)  -> y grad
        const v2 fpx = P1x + B, fpy = P1y + C, fpz = A - P1z;
        P1x = 2.f*B + P2x;  P1y = 2.f*C + P2y;  P1z = P2z;
        P2x = B;  P2y = C;  P2z = A;

        const v4 sm_ = cmb[s][1][r][gx], s0_ = cmb[s][1][r + 1][gx], sp_ = cmb[s][1][r + 2][gx];
        const v2 At = sm_.xy + 2.f*s0_.xy + sp_.xy;
        const v2 Bt = sm_.zw + 2.f*s0_.zw + sp_.zw;
        const v2 Ct = sp_.xy - sm_.xy;
        const v2 ftx = T1x + Bt, fty = T1y + Ct, ftz = At - T1z;
        T1x = 2.f*Bt + T2x;  T1y = 2.f*Ct + T2y;  T1z = T2z;
        T2x = Bt;  T2y = Ct;  T2z = At;

        if (p >= 2) {
            // fused: (pm-tm)^2 = a+b-2*sqrt(ab); rsq(n1)*rsq(n2)=rsq(n1*n2)
            const v2 np2 = fpx*fpx + fpy*fpy + fpz*fpz;
            const v2 nt2 = ftx*ftx + fty*fty + ftz*ftz;
            const v2 a  = np2 + 1e-8f;
            const v2 bb = nt2 + 1e-8f;
            const v2 ab = a * bb;
            v2 rt;
            rt.x = __builtin_amdgcn_sqrtf(ab.x);
            rt.y = __builtin_amdgcn_sqrtf(ab.y);
            accm += a + bb - 2.f*rt;
            const v2 dt = fpx*ftx + fpy*fty + fpz*ftz;
            v2 pr = np2 * nt2;
            pr.x = fmaxf(pr.x, 1e-30f);
            pr.y = fmaxf(pr.y, 1e-30f);
            v2 rq;
            rq.x = __builtin_amdgcn_rsqf(pr.x);
            rq.y = __builtin_amdgcn_rsqf(pr.y);
            accc += dt * rq;
        }
    };

    // ---- prologue: combo-write planes 0-2; issue loads for planes 3-5 ----
    issueG(pA4, pA2, sA4, sA2, 0);
    issueG(pB4, pB2, sB4, sB2, 1);
    issueG(pC4, pC2, sC4, sC2, 2);
    comboWrite(pA4, pA2, sA4, sA2, 0, 0);   // vmcnt waits inserted by compiler
    comboWrite(pB4, pB2, sB4, sB2, 1, 1);
    comboWrite(pC4, pC2, sC4, sC2, 2, 2);
    issueG(pA4, pA2, sA4, sA2, 3);
    issueG(pB4, pB2, sB4, sB2, 4);
    issueG(pC4, pC2, sC4, sC2, 5);
    __syncthreads();

    #pragma unroll 1   // CRITICAL: rolled (R16 lesson)
    for (int pp = 0; pp < PLANES; pp += 3) {
        const int s  = (pp / 3 % 2) * 3;   // 0,3,0,3,... this triple's slots
        const int s2 = s ^ 3;              // next triple's slots

        consume(pp,     s);
        consume(pp + 1, s + 1);
        consume(pp + 2, s + 2);

        // combo-write next triple (loads have ~1 interval of cover), then
        // issue loads for the triple after. Slots disjoint from consumed.
        if (pp + 3 < PLANES) {
            comboWrite(pA4, pA2, sA4, sA2, pp + 3, s2);
            comboWrite(pB4, pB2, sB4, sB2, pp + 4, s2 + 1);
            comboWrite(pC4, pC2, sC4, sC2, pp + 5, s2 + 2);
        }
        if (pp + 6 < PLANES) {
            issueG(pA4, pA2, sA4, sA2, pp + 6);
            issueG(pB4, pB2, sB4, sB2, pp + 7);
            issueG(pC4, pC2, sC4, sC2, pp + 8);
        }

        __syncthreads();   // writes visible; orders slot reuse next interval
    }

    // ---- block reduction ----
    float am = accm.x + accm.y;
    float ac = accc.x + accc.y;
    #pragma unroll
    for (int off = 32; off >= 1; off >>= 1) {
        am += __shfl_down(am, off);
        ac += __shfl_down(ac, off);
    }
    const int wid = tid >> 6;
    if ((tid & 63) == 0) { rred[wid] = am; rred[4 + wid] = ac; }
    __syncthreads();
    if (tid == 0) {
        const float m = rred[0] + rred[1] + rred[2] + rred[3];
        const float c = rred[4] + rred[5] + rred[6] + rred[7];
        partial[bid] = make_float2(m, c);
    }
}

__global__ __launch_bounds__(256)
void acl_final(const float2* __restrict__ partial, float* __restrict__ out)
{
    __shared__ double sm[256], sc[256];
    double m = 0.0, c = 0.0;
    for (int i = threadIdx.x; i < NBLOCKS; i += 256) {
        const float2 v = partial[i];
        m += (double)v.x;
        c += (double)v.y;
    }
    sm[threadIdx.x] = m;
    sc[threadIdx.x] = c;
    __syncthreads();
    #pragma unroll
    for (int s = 128; s >= 1; s >>= 1) {
        if (threadIdx.x < (unsigned)s) {
            sm[threadIdx.x] += sm[threadIdx.x + s];
            sc[threadIdx.x] += sc[threadIdx.x + s];
        }
        __syncthreads();
    }
    if (threadIdx.x == 0) {
        const double mag_loss = sm[0] / NVOX;
        const double dir_loss = 1.0 - sc[0] / NVOX;
        out[0] = (float)(0.2 * (mag_loss + dir_loss));
    }
}

extern "C" void kernel_launch(void* const* d_in, const int* in_sizes, int n_in,
                              void* d_out, int out_size, void* d_ws, size_t ws_size,
                              hipStream_t stream) {
    const float* pred = (const float*)d_in[0];
    const float* targ = (const float*)d_in[1];
    float* out = (float*)d_out;
    float2* partial = (float2*)d_ws;  // 1000 * 8 B = 8 KB

    acl_partial<<<NBLOCKS, 256, 0, stream>>>(pred, targ, partial);
    acl_final<<<1, 256, 0, stream>>>(partial, out);
}

// Round 30
// 28.470 us; speedup vs baseline: 1.1754x; 1.1754x over previous
//
#include <hip/hip_runtime.h>

// AnatomicalConsistencyLoss: fused separable-Sobel magnitude + cosine loss.
// pred/target (2,1,160,160,160) f32 -> scalar f32.
// R30 = R28 EXACTLY (best: 28.41us). R29's 3-plane interval regressed via
// LDS-occupancy (58.8KB -> 2 blocks/CU -> 17.7% occupancy): the combo
// structure's optimum is 2 planes/interval @ 39.2KB (4 blocks/CU).
// Structure: combo-staged LDS (HS/HD computed once per item, interleaved
// {HS.xy,HD.xy} v4 pairs; consume = 3 aligned b128/vol, mask-free),
// load-balanced 288 per-volume items over 256 threads, dual prefetch sets,
// 2-plane barrier intervals (9 barriers), pending-sum z-stream, packed-v2
// loss tail, fused transcendentals, XCD-chunked bijective swizzle,
// DC=16/1000 blocks, two-kernel finalize, unroll pinned.

constexpr int Dd = 160, Hh = 160, Ww = 160;
constexpr int TW = 32, TH = 16, DC = 16;
constexpr int NTX = Ww / TW;                 // 5
constexpr int NTY = Hh / TH;                 // 10
constexpr int NTZ = Dd / DC;                 // 10
constexpr int NBLOCKS = NTX * NTY * NTZ * 2; // 1000
constexpr int NXCD = 8;
constexpr int CHUNK = NBLOCKS / NXCD;        // 125
constexpr int PLANES = DC + 2;               // 18 = 9 intervals x 2 planes
constexpr int PLSZ = Hh * Ww;                // 25600
constexpr double NVOX = 2.0 * Dd * Hh * Ww;  // 8,192,000

constexpr int CROWS = TH + 2;                // 18 combo rows
constexpr int CGP   = 17;                    // padded group stride (v4 units)

typedef float v2 __attribute__((ext_vector_type(2)));
typedef float v4 __attribute__((ext_vector_type(4)));
typedef float v4a __attribute__((ext_vector_type(4), aligned(4)));  // dword-aligned ok
typedef float v2a __attribute__((ext_vector_type(2), aligned(4)));

__global__ __launch_bounds__(256)
void acl_partial(const float* __restrict__ pred, const float* __restrict__ targ,
                 float2* __restrict__ partial)
{
    // {HS.xy, HD.xy} per 2-col group; b128-aligned; row stride 17 v4s (pad)
    __shared__ v4 cmb[4][2][CROWS][CGP];   // [slot][vol][row][grp], 39.2 KB
    __shared__ float rred[8];

    const int tid = threadIdx.x;
    const int gx  = tid & 15;        // consume: x-group of 2 output cols
    const int r   = tid >> 4;        // consume: row 0..15

    // ---- XCD-chunked bijective swizzle + decode (zt fastest, wt, ht, b) ----
    const int bid = blockIdx.x;
    const int swz = (bid % NXCD) * CHUNK + bid / NXCD;
    const int zt  = swz % NTZ;
    const int t1  = swz / NTZ;
    const int wt  = t1 % NTX;
    const int t2  = t1 / NTX;
    const int ht  = t2 % NTY;
    const int b   = t2 / NTY;

    const int x0 = wt * TW, y0 = ht * TH;
    const int z0 = zt * DC;
    const size_t base = (size_t)b * ((size_t)Dd * PLSZ);
    const float* __restrict__ pv = pred + base;
    const float* __restrict__ tv = targ + base;

    // ---- per-volume combo items: vitem v in [0,288): row=v>>4, sub=v&15,
    //      vol=sub&1, cg=sub>>1. Primary = tid; secondary (tid<32) = 256+tid.
    const bool hasSec = (tid < 32);

    struct ItemC { int a4, a2, bo; bool fixLo, fixHi, yok, isT; };
    auto mkItem = [&](int v, ItemC& it) {
        const int row = v >> 4;
        const int sub = v & 15;
        const int vol = sub & 1;
        const int cg  = sub >> 1;
        const int gy  = y0 - 1 + row;
        it.yok = (gy >= 0) && (gy < Hh);
        const int gycl = gy < 0 ? 0 : (gy > Hh - 1 ? Hh - 1 : gy);
        it.fixLo = (x0 == 0) && (cg == 0);
        it.fixHi = (x0 + TW == Ww) && (cg == 7);
        const int xb = x0 + 4 * cg - 1;
        it.a4 = gycl * Ww + (it.fixLo ? 0 : xb);              // v4: e0..e3 (or e1..e4)
        it.a2 = gycl * Ww + (it.fixHi ? (Ww - 2) : (xb + 4)); // v2: e4,e5 (or e3,e4)
        it.bo = (vol * CROWS + row) * CGP + 2 * cg;           // v4 offset in slot
        it.isT = (vol != 0);
    };
    ItemC itP, itS;
    mkItem(tid, itP);
    mkItem(hasSec ? 256 + tid : tid, itS);   // dummy for non-sec (never used)

    const v2 z2 = {0.f, 0.f};
    const v4 z4 = {0.f, 0.f, 0.f, 0.f};

    // streaming pending partial gradients (named v2 scalars only)
    v2 P1x = z2, P1y = z2, P1z = z2, P2x = z2, P2y = z2, P2z = z2;
    v2 T1x = z2, T1y = z2, T1z = z2, T2x = z2, T2y = z2, T2z = z2;
    v2 accm = z2, accc = z2;

    // dual prefetch reg sets A/B (12 dwords each: primary v4+v2, secondary v4+v2)
    v4 pA4 = z4, sA4 = z4, pB4 = z4, sB4 = z4;
    v2 pA2 = z2, sA2 = z2, pB2 = z2, sB2 = z2;

    auto issueG = [&](v4& q4, v2& q2, v4& s4, v2& s2, int p2) {
        int gz = z0 - 1 + p2;
        gz = gz < 0 ? 0 : (gz > Dd - 1 ? Dd - 1 : gz);
        const float* zp = (itP.isT ? tv : pv) + (ptrdiff_t)gz * PLSZ;
        q4 = *(const v4a*)(zp + itP.a4);
        q2 = *(const v2a*)(zp + itP.a2);
        if (hasSec) {
            const float* zs = (itS.isT ? tv : pv) + (ptrdiff_t)gz * PLSZ;
            s4 = *(const v4a*)(zs + itS.a4);
            s2 = *(const v2a*)(zs + itS.a2);
        }
    };

    // assemble e0..e5 from the two loads, honoring edge fixups
    auto comboOne = [&](const ItemC& it, const v4 v, const v2 u, v4& w0, v4& w1) {
        float e0, e1, e2, e3, e4, e5;
        if (it.fixLo)      { e0 = 0.f;  e1 = v.x; e2 = v.y; e3 = v.z; e4 = v.w; e5 = u.y; }
        else if (it.fixHi) { e0 = v.x;  e1 = v.y; e2 = v.z; e3 = v.w; e4 = u.y; e5 = 0.f; }
        else               { e0 = v.x;  e1 = v.y; e2 = v.z; e3 = v.w; e4 = u.x; e5 = u.y; }
        const float HS0 = e0 + 2.f*e1 + e2, HS1 = e1 + 2.f*e2 + e3;
        const float HS2 = e2 + 2.f*e3 + e4, HS3 = e3 + 2.f*e4 + e5;
        w0 = (v4){HS0, HS1, e2 - e0, e3 - e1};
        w1 = (v4){HS2, HS3, e4 - e2, e5 - e3};
    };

    auto comboWrite = [&](const v4 q4, const v2 q2, const v4 s4, const v2 s2,
                          int p1, int slot) {
        const bool zokc = ((unsigned)(z0 - 1 + p1) < (unsigned)Dd);
        v4* sb = &cmb[slot][0][0][0];
        v4 w0, w1;
        comboOne(itP, q4, q2, w0, w1);
        if (!(zokc && itP.yok)) { w0 = z4; w1 = z4; }
        sb[itP.bo]     = w0;
        sb[itP.bo + 1] = w1;
        if (hasSec) {
            comboOne(itS, s4, s2, w0, w1);
            if (!(zokc && itS.yok)) { w0 = z4; w1 = z4; }
            sb[itS.bo]     = w0;
            sb[itS.bo + 1] = w1;
        }
    };

    auto consume = [&](int p, int s) {
        const v4 qm = cmb[s][0][r][gx], q0 = cmb[s][0][r + 1][gx], qp = cmb[s][0][r + 2][gx];
        const v2 A = qm.xy + 2.f*q0.xy + qp.xy;   // sm_y(HS) -> z path
        const v2 B = qm.zw + 2.f*q0.zw + qp.zw;   // sm_y(HD) -> x grad
        const v2 C = qp.xy - qm.xy;               // d_y(HS)  -> y grad
        const v2 fpx = P1x + B, fpy = P1y + C, fpz = A - P1z;
        P1x = 2.f*B + P2x;  P1y = 2.f*C + P2y;  P1z = P2z;
        P2x = B;  P2y = C;  P2z = A;

        const v4 sm_ = cmb[s][1][r][gx], s0_ = cmb[s][1][r + 1][gx], sp_ = cmb[s][1][r + 2][gx];
        const v2 At = sm_.xy + 2.f*s0_.xy + sp_.xy;
        const v2 Bt = sm_.zw + 2.f*s0_.zw + sp_.zw;
        const v2 Ct = sp_.xy - sm_.xy;
        const v2 ftx = T1x + Bt, fty = T1y + Ct, ftz = At - T1z;
        T1x = 2.f*Bt + T2x;  T1y = 2.f*Ct + T2y;  T1z = T2z;
        T2x = Bt;  T2y = Ct;  T2z = At;

        if (p >= 2) {
            // fused: (pm-tm)^2 = a+b-2*sqrt(ab); rsq(n1)*rsq(n2)=rsq(n1*n2)
            const v2 np2 = fpx*fpx + fpy*fpy + fpz*fpz;
            const v2 nt2 = ftx*ftx + fty*fty + ftz*ftz;
            const v2 a  = np2 + 1e-8f;
            const v2 bb = nt2 + 1e-8f;
            const v2 ab = a * bb;
            v2 rt;
            rt.x = __builtin_amdgcn_sqrtf(ab.x);
            rt.y = __builtin_amdgcn_sqrtf(ab.y);
            accm += a + bb - 2.f*rt;
            const v2 dt = fpx*ftx + fpy*fty + fpz*ftz;
            v2 pr = np2 * nt2;
            pr.x = fmaxf(pr.x, 1e-30f);
            pr.y = fmaxf(pr.y, 1e-30f);
            v2 rq;
            rq.x = __builtin_amdgcn_rsqf(pr.x);
            rq.y = __builtin_amdgcn_rsqf(pr.y);
            accc += dt * rq;
        }
    };

    // ---- prologue: combo-write planes 0,1; issue loads for planes 2,3 ----
    issueG(pA4, pA2, sA4, sA2, 0);
    issueG(pB4, pB2, sB4, sB2, 1);
    comboWrite(pA4, pA2, sA4, sA2, 0, 0);   // vmcnt wait inserted by compiler
    comboWrite(pB4, pB2, sB4, sB2, 1, 1);
    issueG(pA4, pA2, sA4, sA2, 2);
    issueG(pB4, pB2, sB4, sB2, 3);
    __syncthreads();

    #pragma unroll 1   // CRITICAL: rolled (R16 lesson)
    for (int pp = 0; pp < PLANES; pp += 2) {
        consume(pp,     pp & 3);
        consume(pp + 1, (pp + 1) & 3);

        // combo-write planes pp+2,pp+3 (loads have 1 interval of cover),
        // then issue loads for pp+4,pp+5. Slots disjoint from consumed ones.
        if (pp + 2 < PLANES) comboWrite(pA4, pA2, sA4, sA2, pp + 2, (pp + 2) & 3);
        if (pp + 3 < PLANES) comboWrite(pB4, pB2, sB4, sB2, pp + 3, (pp + 3) & 3);
        if (pp + 4 < PLANES) issueG(pA4, pA2, sA4, sA2, pp + 4);
        if (pp + 5 < PLANES) issueG(pB4, pB2, sB4, sB2, pp + 5);

        __syncthreads();   // writes visible; orders slot reuse next interval
    }

    // ---- block reduction ----
    float am = accm.x + accm.y;
    float ac = accc.x + accc.y;
    #pragma unroll
    for (int off = 32; off >= 1; off >>= 1) {
        am += __shfl_down(am, off);
        ac += __shfl_down(ac, off);
    }
    const int wid = tid >> 6;
    if ((tid & 63) == 0) { rred[wid] = am; rred[4 + wid] = ac; }
    __syncthreads();
    if (tid == 0) {
        const float m = rred[0] + rred[1] + rred[2] + rred[3];
        const float c = rred[4] + rred[5] + rred[6] + rred[7];
        partial[bid] = make_float2(m, c);
    }
}

__global__ __launch_bounds__(256)
void acl_final(const float2* __restrict__ partial, float* __restrict__ out)
{
    __shared__ double sm[256], sc[256];
    double m = 0.0, c = 0.0;
    for (int i = threadIdx.x; i < NBLOCKS; i += 256) {
        const float2 v = partial[i];
        m += (double)v.x;
        c += (double)v.y;
    }
    sm[threadIdx.x] = m;
    sc[threadIdx.x] = c;
    __syncthreads();
    #pragma unroll
    for (int s = 128; s >= 1; s >>= 1) {
        if (threadIdx.x < (unsigned)s) {
            sm[threadIdx.x] += sm[threadIdx.x + s];
            sc[threadIdx.x] += sc[threadIdx.x + s];
        }
        __syncthreads();
    }
    if (threadIdx.x == 0) {
        const double mag_loss = sm[0] / NVOX;
        const double dir_loss = 1.0 - sc[0] / NVOX;
        out[0] = (float)(0.2 * (mag_loss + dir_loss));
    }
}

extern "C" void kernel_launch(void* const* d_in, const int* in_sizes, int n_in,
                              void* d_out, int out_size, void* d_ws, size_t ws_size,
                              hipStream_t stream) {
    const float* pred = (const float*)d_in[0];
    const float* targ = (const float*)d_in[1];
    float* out = (float*)d_out;
    float2* partial = (float2*)d_ws;  // 1000 * 8 B = 8 KB

    acl_partial<<<NBLOCKS, 256, 0, stream>>>(pred, targ, partial);
    acl_final<<<1, 256, 0, stream>>>(partial, out);
}